// Round 1
// baseline (184.106 us; speedup 1.0000x reference)
//
#include <hip/hip_runtime.h>
#include <hip/hip_bf16.h>

// Problem constants (B,C,T,H,W = 4,128,16,32,32)
#define NB 4
#define NC 128
#define NN 16384   // T*H*W
#define NM 2048    // pooled positions

typedef __attribute__((ext_vector_type(8))) short bf16x8;
typedef __attribute__((ext_vector_type(4))) float f32x4;
typedef __attribute__((ext_vector_type(4))) unsigned short u16x4;
typedef __attribute__((ext_vector_type(2))) unsigned int u32x2;

#define MFMA16(a,b,c) __builtin_amdgcn_mfma_f32_16x16x32_bf16((a),(b),(c),0,0,0)

__device__ __forceinline__ unsigned short f2bf(float f){
  unsigned int u = __float_as_uint(f);
  u += 0x7fffu + ((u >> 16) & 1u);          // RNE
  return (unsigned short)(u >> 16);
}
__device__ __forceinline__ float bf2f(unsigned short h){
  return __uint_as_float(((unsigned int)h) << 16);
}
// pack two positive floats as bf16 pair (truncation; lo in low half)
__device__ __forceinline__ unsigned int packbf2(float lo, float hi){
  return (__float_as_uint(hi) & 0xffff0000u) | (__float_as_uint(lo) >> 16);
}

// ---------------- K0: weight prep (fp32 -> bf16, concat) ----------------
__global__ void k0_prep(const float* __restrict__ wf, const float* __restrict__ wg,
                        const float* __restrict__ wh, const float* __restrict__ bfp,
                        const float* __restrict__ bgp, const float* __restrict__ bhp,
                        const float* __restrict__ wo,
                        unsigned short* __restrict__ Wcat, unsigned short* __restrict__ wob,
                        float* __restrict__ bcat){
  int i = blockIdx.x * 256 + threadIdx.x;
  if (i < 16384){
    int o = i >> 7, c = i & 127;
    float v = (o < 32) ? wf[o*128 + c] : (o < 64) ? wg[(o-32)*128 + c] : wh[(o-64)*128 + c];
    Wcat[i] = f2bf(v);
  } else if (i < 24576){
    wob[i - 16384] = f2bf(wo[i - 16384]);
  } else if (i < 24704){
    int k = i - 24576;
    bcat[k] = (k < 32) ? bfp[k] : (k < 64) ? bgp[k-32] : bhp[k-64];
  }
}

// ---------------- K1: x[b][c][n] fp32 -> xT[b][n][c] bf16 ----------------
__global__ void k1_transpose(const float* __restrict__ x, unsigned short* __restrict__ xT){
  __shared__ float tile[32][33];
  int bx = blockIdx.x;                       // 4 * 4 * 512
  int nb = bx & 511, cb = (bx >> 9) & 3, b = bx >> 11;
  int t = threadIdx.x;
  int row = t >> 3, col4 = (t & 7) * 4;
  const float4 v = *(const float4*)(x + ((size_t)(b*128 + cb*32 + row)) * NN + nb*32 + col4);
  tile[row][col4+0] = v.x; tile[row][col4+1] = v.y;
  tile[row][col4+2] = v.z; tile[row][col4+3] = v.w;
  __syncthreads();
  int n = t >> 3, cv = (t & 7) * 4;
  u16x4 o;
  o[0] = f2bf(tile[cv+0][n]); o[1] = f2bf(tile[cv+1][n]);
  o[2] = f2bf(tile[cv+2][n]); o[3] = f2bf(tile[cv+3][n]);
  *(u16x4*)(xT + ((size_t)(b*NN + nb*32 + n)) * 128 + cb*32 + cv) = o;
}

// ---------------- K2: fused 3-conv (Wcat @ x), relu, theta + w-pooled Yp ----------------
__global__ __launch_bounds__(256, 2) void k2_conv(
    const unsigned short* __restrict__ xT, const unsigned short* __restrict__ Wcat,
    const float* __restrict__ bcat,
    unsigned short* __restrict__ thetaT, unsigned short* __restrict__ Yp){
  int blk = blockIdx.x;                  // NB * NN/64 = 1024
  int b = blk >> 8, nblk = blk & 255;
  int tid = threadIdx.x;
  int lane = tid & 63, w = tid >> 6;
  int ln = lane & 15, gq = lane >> 4;
  int n = nblk*64 + w*16 + ln;
  const unsigned short* xrow = xT + ((size_t)b*NN + n) * 128;
  bf16x8 xf[4];
  #pragma unroll
  for (int kf = 0; kf < 4; ++kf)
    xf[kf] = *(const bf16x8*)(xrow + kf*32 + gq*8);
  #pragma unroll
  for (int ot = 0; ot < 8; ++ot){
    f32x4 acc = {0.f,0.f,0.f,0.f};
    #pragma unroll
    for (int kf = 0; kf < 4; ++kf){
      bf16x8 wfr = *(const bf16x8*)(Wcat + (ot*16 + ln)*128 + kf*32 + gq*8);
      acc = MFMA16(wfr, xf[kf], acc);
    }
    float y[4];
    #pragma unroll
    for (int i = 0; i < 4; ++i){
      int o = ot*16 + gq*4 + i;
      float v = acc[i] + bcat[o];
      y[i] = v > 0.f ? v : 0.f;
    }
    if (ot < 2){
      // theta rows 0..31 -> thetaT[b][n][32]
      u16x4 pk;
      #pragma unroll
      for (int i = 0; i < 4; ++i) pk[i] = f2bf(y[i]);
      *(u16x4*)(thetaT + ((size_t)b*NN + n)*32 + ot*16 + gq*4) = pk;
    } else {
      // rows 32..127: pool over w-pairs now (lanes n even/odd), write Yp[b][r][n>>1]
      #pragma unroll
      for (int i = 0; i < 4; ++i){
        float ym = fmaxf(y[i], __shfl_xor(y[i], 1));
        if ((ln & 1) == 0){
          int r = ot*16 + gq*4 + i - 32;
          Yp[((size_t)b*96 + r)*8192 + (n >> 1)] = f2bf(ym);
        }
      }
    }
  }
}

// ---------------- K3: pool t/h pairs -> phiT[b][m][32], g[b][c2][m] ----------------
__global__ void k3_pool(const unsigned short* __restrict__ Yp,
                        unsigned short* __restrict__ phiT, unsigned short* __restrict__ g_){
  int i = blockIdx.x*256 + threadIdx.x;
  if (i < 262144){                              // NB*NM*32, c fastest
    int c = i & 31, m = (i >> 5) & 2047, b = i >> 16;
    int tq = m >> 8, hq = (m >> 4) & 15, wq = m & 15;
    size_t base = ((size_t)b*96 + c)*8192 + tq*1024 + hq*32 + wq;
    float v0 = bf2f(Yp[base]),     v1 = bf2f(Yp[base+16]);
    float v2 = bf2f(Yp[base+512]), v3 = bf2f(Yp[base+528]);
    phiT[((size_t)b*NM + m)*32 + c] = f2bf(fmaxf(fmaxf(v0,v1), fmaxf(v2,v3)));
  } else if (i < 262144 + 524288){              // NB*64*NM, m fastest
    int j = i - 262144;
    int m = j & 2047, c2 = (j >> 11) & 63, b = j >> 17;
    int tq = m >> 8, hq = (m >> 4) & 15, wq = m & 15;
    size_t base = ((size_t)b*96 + 32 + c2)*8192 + tq*1024 + hq*32 + wq;
    float v0 = bf2f(Yp[base]),     v1 = bf2f(Yp[base+16]);
    float v2 = bf2f(Yp[base+512]), v3 = bf2f(Yp[base+528]);
    g_[((size_t)b*64 + c2)*NM + m] = f2bf(fmaxf(fmaxf(v0,v1), fmaxf(v2,v3)));
  }
}

// ---------------- K4: flash attention (no-max softmax; scores >= 0, bounded) ----------------
__global__ __launch_bounds__(256, 2) void k4_attn(
    const unsigned short* __restrict__ thetaT, const unsigned short* __restrict__ phiT,
    const unsigned short* __restrict__ g_, unsigned short* __restrict__ attn_gT){
  __shared__ __align__(16) unsigned short phi_lds[2][32][40];
  __shared__ __align__(16) unsigned short g_lds[2][64][40];
  __shared__ __align__(16) unsigned short P_lds[4][16][40];

  int b = blockIdx.x >> 7, qb = blockIdx.x & 127;    // grid 512
  int tid = threadIdx.x;
  int lane = tid & 63, wv = tid >> 6;
  int ln = lane & 15, gq = lane >> 4;
  int nq = qb*128 + wv*32;                           // 32 queries per wave (2 tiles)

  const unsigned short* thb = thetaT + (size_t)b*NN*32;
  const unsigned short* phb = phiT   + (size_t)b*NM*32;
  const unsigned short* gb  = g_     + (size_t)b*64*NM;

  bf16x8 thf0 = *(const bf16x8*)(thb + (size_t)(nq + ln)*32 + gq*8);
  bf16x8 thf1 = *(const bf16x8*)(thb + (size_t)(nq + 16 + ln)*32 + gq*8);

  f32x4 acc[2][4];
  #pragma unroll
  for (int q = 0; q < 2; ++q)
    #pragma unroll
    for (int c2t = 0; c2t < 4; ++c2t) acc[q][c2t] = (f32x4){0.f,0.f,0.f,0.f};
  float lsum0 = 0.f, lsum1 = 0.f;

  // staging: g by all 256 threads; phi by tid<128
  int gr = tid >> 2, gp = tid & 3;
  const unsigned short* sgp_g = gb + (size_t)gr*NM + gp*8;
  unsigned short* slg0 = &g_lds[0][gr][gp*8];
  unsigned short* slg1 = &g_lds[1][gr][gp*8];
  bool hasphi = tid < 128;
  int pr = (tid >> 2) & 31, pp = tid & 3;
  const unsigned short* sgp_p = phb + pr*32 + pp*8;
  unsigned short* slp0 = &phi_lds[0][pr][pp*8];
  unsigned short* slp1 = &phi_lds[1][pr][pp*8];

  { bf16x8 srg = *(const bf16x8*)(sgp_g); *(bf16x8*)slg0 = srg; }
  if (hasphi){ bf16x8 srp = *(const bf16x8*)(sgp_p); *(bf16x8*)slp0 = srp; }
  __syncthreads();

  bf16x8 srg_n = {}, srp_n = {};
  for (int ch = 0; ch < 64; ++ch){
    int cur = ch & 1;
    if (ch + 1 < 64){                             // issue-early (T14)
      srg_n = *(const bf16x8*)(sgp_g + (size_t)(ch+1)*32);
      if (hasphi) srp_n = *(const bf16x8*)(sgp_p + (size_t)(ch+1)*1024);
    }
    bf16x8 pf0 = *(const bf16x8*)(&phi_lds[cur][ln][gq*8]);
    bf16x8 pf1 = *(const bf16x8*)(&phi_lds[cur][16+ln][gq*8]);
    bf16x8 gf0 = *(const bf16x8*)(&g_lds[cur][ln][gq*8]);
    bf16x8 gf1 = *(const bf16x8*)(&g_lds[cur][16+ln][gq*8]);
    bf16x8 gf2 = *(const bf16x8*)(&g_lds[cur][32+ln][gq*8]);
    bf16x8 gf3 = *(const bf16x8*)(&g_lds[cur][48+ln][gq*8]);
    f32x4 z = {0.f,0.f,0.f,0.f};

    // ---- q tile 0 ----
    {
      f32x4 s0 = MFMA16(pf0, thf0, z);
      f32x4 s1 = MFMA16(pf1, thf0, z);
      float p0[4], p1[4];
      #pragma unroll
      for (int i = 0; i < 4; ++i){ p0[i] = __expf(s0[i]); p1[i] = __expf(s1[i]); }
      lsum0 += ((p0[0]+p0[1]) + (p0[2]+p0[3])) + ((p1[0]+p1[1]) + (p1[2]+p1[3]));
      u32x2 w0 = { packbf2(p0[0],p0[1]), packbf2(p0[2],p0[3]) };
      u32x2 w1 = { packbf2(p1[0],p1[1]), packbf2(p1[2],p1[3]) };
      *(u32x2*)(&P_lds[wv][ln][gq*4])      = w0;
      *(u32x2*)(&P_lds[wv][ln][16+gq*4])   = w1;
      bf16x8 paf = *(const bf16x8*)(&P_lds[wv][ln][gq*8]);
      acc[0][0] = MFMA16(paf, gf0, acc[0][0]);
      acc[0][1] = MFMA16(paf, gf1, acc[0][1]);
      acc[0][2] = MFMA16(paf, gf2, acc[0][2]);
      acc[0][3] = MFMA16(paf, gf3, acc[0][3]);
    }
    // ---- q tile 1 ----
    {
      f32x4 s0 = MFMA16(pf0, thf1, z);
      f32x4 s1 = MFMA16(pf1, thf1, z);
      float p0[4], p1[4];
      #pragma unroll
      for (int i = 0; i < 4; ++i){ p0[i] = __expf(s0[i]); p1[i] = __expf(s1[i]); }
      lsum1 += ((p0[0]+p0[1]) + (p0[2]+p0[3])) + ((p1[0]+p1[1]) + (p1[2]+p1[3]));
      u32x2 w0 = { packbf2(p0[0],p0[1]), packbf2(p0[2],p0[3]) };
      u32x2 w1 = { packbf2(p1[0],p1[1]), packbf2(p1[2],p1[3]) };
      *(u32x2*)(&P_lds[wv][ln][gq*4])      = w0;
      *(u32x2*)(&P_lds[wv][ln][16+gq*4])   = w1;
      bf16x8 paf = *(const bf16x8*)(&P_lds[wv][ln][gq*8]);
      acc[1][0] = MFMA16(paf, gf0, acc[1][0]);
      acc[1][1] = MFMA16(paf, gf1, acc[1][1]);
      acc[1][2] = MFMA16(paf, gf2, acc[1][2]);
      acc[1][3] = MFMA16(paf, gf3, acc[1][3]);
    }
    if (ch + 1 < 64){                             // write-late into other buffer
      *(bf16x8*)(((ch+1)&1) ? slg1 : slg0) = srg_n;
      if (hasphi) *(bf16x8*)(((ch+1)&1) ? slp1 : slp0) = srp_n;
    }
    __syncthreads();
  }

  lsum0 += __shfl_xor(lsum0, 16); lsum0 += __shfl_xor(lsum0, 32);
  lsum1 += __shfl_xor(lsum1, 16); lsum1 += __shfl_xor(lsum1, 32);

  unsigned short* agb = attn_gT + (size_t)b*NN*64;
  #pragma unroll
  for (int i = 0; i < 4; ++i){
    float li0 = 1.0f / __shfl(lsum0, gq*4 + i);
    float li1 = 1.0f / __shfl(lsum1, gq*4 + i);
    int r0 = nq + gq*4 + i, r1 = nq + 16 + gq*4 + i;
    #pragma unroll
    for (int c2t = 0; c2t < 4; ++c2t){
      agb[(size_t)r0*64 + c2t*16 + ln] = f2bf(acc[0][c2t][i] * li0);
      agb[(size_t)r1*64 + c2t*16 + ln] = f2bf(acc[1][c2t][i] * li1);
    }
  }
}

// ---------------- K5: out = x + gamma*relu(wo @ attn_g + bo) ----------------
__global__ __launch_bounds__(256, 2) void k5_out(
    const float* __restrict__ x, const unsigned short* __restrict__ attn_gT,
    const unsigned short* __restrict__ wob, const float* __restrict__ bo,
    const float* __restrict__ gamma, float* __restrict__ out){
  int blk = blockIdx.x;                 // NB * NN/64 = 1024
  int b = blk >> 8, nblk = blk & 255;
  int tid = threadIdx.x;
  int lane = tid & 63, w = tid >> 6;
  int ln = lane & 15, gq = lane >> 4;
  int n = nblk*64 + w*16 + ln;
  const unsigned short* ag = attn_gT + ((size_t)b*NN + n)*64;
  bf16x8 bfr0 = *(const bf16x8*)(ag + gq*8);
  bf16x8 bfr1 = *(const bf16x8*)(ag + 32 + gq*8);
  float gam = gamma[0];
  #pragma unroll
  for (int ot = 0; ot < 8; ++ot){
    f32x4 acc = {0.f,0.f,0.f,0.f};
    bf16x8 a0 = *(const bf16x8*)(wob + (ot*16 + ln)*64 + gq*8);
    bf16x8 a1 = *(const bf16x8*)(wob + (ot*16 + ln)*64 + 32 + gq*8);
    acc = MFMA16(a0, bfr0, acc);
    acc = MFMA16(a1, bfr1, acc);
    #pragma unroll
    for (int i = 0; i < 4; ++i){
      int o = ot*16 + gq*4 + i;
      size_t idx = ((size_t)b*128 + o)*NN + n;
      float v = acc[i] + bo[o];
      v = v > 0.f ? v : 0.f;
      out[idx] = x[idx] + gam * v;
    }
  }
}

extern "C" void kernel_launch(void* const* d_in, const int* in_sizes, int n_in,
                              void* d_out, int out_size, void* d_ws, size_t ws_size,
                              hipStream_t stream){
  const float* x   = (const float*)d_in[0];
  const float* wf  = (const float*)d_in[1];
  const float* bfp = (const float*)d_in[2];
  const float* wg  = (const float*)d_in[3];
  const float* bgp = (const float*)d_in[4];
  const float* wh  = (const float*)d_in[5];
  const float* bhp = (const float*)d_in[6];
  const float* wo  = (const float*)d_in[7];
  const float* bo  = (const float*)d_in[8];
  const float* gam = (const float*)d_in[9];
  float* out = (float*)d_out;
  char* ws = (char*)d_ws;

  const size_t OFF_WCAT = 0;
  const size_t OFF_WO   = 32768;
  const size_t OFF_BCAT = 49152;
  const size_t OFF_XT   = 65536;
  const size_t OFF_TH   = OFF_XT + (size_t)NB*NN*128*2;   // 16842752
  const size_t OFF_YP   = OFF_TH + (size_t)NB*NN*32*2;    // 21037056
  const size_t OFF_PHI  = OFF_YP + (size_t)NB*96*8192*2;  // 27328512
  const size_t OFF_G    = OFF_PHI + (size_t)NB*NM*32*2;   // 27852800 (end 28901376)

  unsigned short* Wcat    = (unsigned short*)(ws + OFF_WCAT);
  unsigned short* wob     = (unsigned short*)(ws + OFF_WO);
  float*          bcat    = (float*)(ws + OFF_BCAT);
  unsigned short* xT      = (unsigned short*)(ws + OFF_XT);
  unsigned short* thetaT  = (unsigned short*)(ws + OFF_TH);
  unsigned short* Yp      = (unsigned short*)(ws + OFF_YP);
  unsigned short* phiT    = (unsigned short*)(ws + OFF_PHI);
  unsigned short* g_      = (unsigned short*)(ws + OFF_G);
  unsigned short* attn_gT = xT;   // alias: xT dead after k2_conv

  k0_prep<<<97, 256, 0, stream>>>(wf, wg, wh, bfp, bgp, bhp, wo, Wcat, wob, bcat);
  k1_transpose<<<8192, 256, 0, stream>>>(x, xT);
  k2_conv<<<1024, 256, 0, stream>>>(xT, Wcat, bcat, thetaT, Yp);
  k3_pool<<<3072, 256, 0, stream>>>(Yp, phiT, g_);
  k4_attn<<<512, 256, 0, stream>>>(thetaT, phiT, g_, attn_gT);
  k5_out<<<1024, 256, 0, stream>>>(x, attn_gT, wob, bo, gam, out);
}

// Round 2
// 169.956 us; speedup vs baseline: 1.0833x; 1.0833x over previous
//
#include <hip/hip_runtime.h>
#include <hip/hip_bf16.h>

// Problem constants (B,C,T,H,W = 4,128,16,32,32)
#define NB 4
#define NC 128
#define NN 16384   // T*H*W
#define NM 2048    // pooled positions

typedef __attribute__((ext_vector_type(8))) short bf16x8;
typedef __attribute__((ext_vector_type(4))) float f32x4;
typedef __attribute__((ext_vector_type(4))) unsigned short u16x4;
typedef __attribute__((ext_vector_type(2))) unsigned int u32x2;

#define MFMA16(a,b,c) __builtin_amdgcn_mfma_f32_16x16x32_bf16((a),(b),(c),0,0,0)

__device__ __forceinline__ unsigned short f2bf(float f){
  unsigned int u = __float_as_uint(f);
  u += 0x7fffu + ((u >> 16) & 1u);          // RNE
  return (unsigned short)(u >> 16);
}
__device__ __forceinline__ float bf2f(unsigned short h){
  return __uint_as_float(((unsigned int)h) << 16);
}
// pack two positive floats as bf16 pair (truncation; lo in low half)
__device__ __forceinline__ unsigned int packbf2(float lo, float hi){
  return (__float_as_uint(hi) & 0xffff0000u) | (__float_as_uint(lo) >> 16);
}

// ---------------- K0: weight prep (fp32 -> bf16, concat) ----------------
__global__ void k0_prep(const float* __restrict__ wf, const float* __restrict__ wg,
                        const float* __restrict__ wh, const float* __restrict__ bfp,
                        const float* __restrict__ bgp, const float* __restrict__ bhp,
                        const float* __restrict__ wo,
                        unsigned short* __restrict__ Wcat, unsigned short* __restrict__ wob,
                        float* __restrict__ bcat){
  int i = blockIdx.x * 256 + threadIdx.x;
  if (i < 16384){
    int o = i >> 7, c = i & 127;
    float v = (o < 32) ? wf[o*128 + c] : (o < 64) ? wg[(o-32)*128 + c] : wh[(o-64)*128 + c];
    Wcat[i] = f2bf(v);
  } else if (i < 24576){
    wob[i - 16384] = f2bf(wo[i - 16384]);
  } else if (i < 24704){
    int k = i - 24576;
    bcat[k] = (k < 32) ? bfp[k] : (k < 64) ? bgp[k-32] : bhp[k-64];
  }
}

// ---------------- K2: fused transpose + 3-conv + relu + w/h-pool ----------------
// block: 64 consecutive n (one t, an h-pair, all w) x all 128 c
__global__ __launch_bounds__(256, 4) void k2_conv(
    const float* __restrict__ x, const unsigned short* __restrict__ Wcat,
    const float* __restrict__ bcat,
    unsigned short* __restrict__ thetaT, unsigned short* __restrict__ Ywh){
  __shared__ __align__(16) unsigned short xtile[64][132];  // [n_local][c], pitch 132
  __shared__ unsigned short Ytmp[96][33];                  // w-pooled rows 32..127
  int blk = blockIdx.x;                  // NB * NN/64 = 1024
  int b = blk >> 8, nblk = blk & 255;
  int n0 = nblk * 64;
  int tid = threadIdx.x;

  // stage x[b][c][n0..n0+63] fp32 -> xtile[n][c] bf16 (transpose)
  {
    int c = tid >> 1, half = tid & 1;
    const float* xr = x + ((size_t)(b*128 + c)) * NN + n0 + half*32;
    #pragma unroll
    for (int j = 0; j < 8; ++j){
      float4 v = *(const float4*)(xr + j*4);
      int nl = half*32 + j*4;
      xtile[nl+0][c] = f2bf(v.x);
      xtile[nl+1][c] = f2bf(v.y);
      xtile[nl+2][c] = f2bf(v.z);
      xtile[nl+3][c] = f2bf(v.w);
    }
  }
  __syncthreads();

  int lane = tid & 63, w = tid >> 6;
  int ln = lane & 15, gq = lane >> 4;
  int n = n0 + w*16 + ln;
  bf16x8 xf[4];
  #pragma unroll
  for (int kf = 0; kf < 4; ++kf)
    xf[kf] = *(const bf16x8*)(&xtile[w*16 + ln][kf*32 + gq*8]);

  #pragma unroll
  for (int ot = 0; ot < 8; ++ot){
    f32x4 acc = {0.f,0.f,0.f,0.f};
    #pragma unroll
    for (int kf = 0; kf < 4; ++kf){
      bf16x8 wfr = *(const bf16x8*)(Wcat + (ot*16 + ln)*128 + kf*32 + gq*8);
      acc = MFMA16(wfr, xf[kf], acc);
    }
    float y[4];
    #pragma unroll
    for (int i = 0; i < 4; ++i){
      int o = ot*16 + gq*4 + i;
      float v = acc[i] + bcat[o];
      y[i] = v > 0.f ? v : 0.f;
    }
    if (ot < 2){
      // theta rows 0..31 -> thetaT[b][n][32]
      u16x4 pk;
      #pragma unroll
      for (int i = 0; i < 4; ++i) pk[i] = f2bf(y[i]);
      *(u16x4*)(thetaT + ((size_t)b*NN + n)*32 + ot*16 + gq*4) = pk;
    } else {
      // rows 32..127: w-pool (lane pairs) -> Ytmp[r][n_local>>1]
      #pragma unroll
      for (int i = 0; i < 4; ++i){
        float ym = fmaxf(y[i], __shfl_xor(y[i], 1));
        if ((ln & 1) == 0){
          int r = ot*16 + gq*4 + i - 32;
          Ytmp[r][(w*16 + ln) >> 1] = f2bf(ym);
        }
      }
    }
  }
  __syncthreads();

  // h-pool: Ytmp[r][j] vs Ytmp[r][j+16] -> Ywh[b][r][t][h2*16 + j]
  int tt = n0 >> 10;          // t index 0..15
  int h2 = nblk & 15;         // h-pair index 0..15
  #pragma unroll
  for (int q = 0; q < 6; ++q){
    int idx = q*256 + tid;    // 0..1535 = 96 r x 16 j
    int r = idx >> 4, j = idx & 15;
    unsigned short a = Ytmp[r][j], bsh = Ytmp[r][j+16];
    unsigned short v = a > bsh ? a : bsh;   // bf16 >=0: unsigned compare == fmax
    Ywh[(((size_t)(b*96 + r))*16 + tt)*256 + h2*16 + j] = v;
  }
}

// ---------------- K3: t-pool -> phiT[b][m][32], g[b][c2][m] ----------------
__global__ void k3_pool(const unsigned short* __restrict__ Ywh,
                        unsigned short* __restrict__ phiT, unsigned short* __restrict__ g_){
  __shared__ unsigned short trans[64][36];
  int blk = blockIdx.x;
  int t = threadIdx.x;
  if (blk < 128){
    // phi: rows 0..31, LDS transpose to [m][c]
    int b = blk >> 5, mseg = blk & 31;
    int m0 = mseg * 64;
    int u = m0 >> 8, p0 = m0 & 255;
    int c = t >> 3, mj = t & 7;
    const unsigned short* r0 = Ywh + (((size_t)(b*96 + c))*16 + 2*u)*256 + p0 + mj*8;
    const unsigned short* r1 = r0 + 256;
    #pragma unroll
    for (int k = 0; k < 8; ++k){
      unsigned short a = r0[k], bsh = r1[k];
      trans[mj*8 + k][c] = a > bsh ? a : bsh;
    }
    __syncthreads();
    int ml = t >> 2, cg = t & 3;
    u16x4 o0, o1;
    #pragma unroll
    for (int k = 0; k < 4; ++k){ o0[k] = trans[ml][cg*8 + k]; o1[k] = trans[ml][cg*8 + 4 + k]; }
    *(u16x4*)(phiT + ((size_t)b*NM + m0 + ml)*32 + cg*8)     = o0;
    *(u16x4*)(phiT + ((size_t)b*NM + m0 + ml)*32 + cg*8 + 4) = o1;
  } else {
    // g: rows 32..95 -> g[b][c2][m], coalesced
    int blk2 = blk - 128;
    int b = blk2 >> 6, c2 = blk2 & 63;
    int u = t >> 5, p = (t & 31) * 8;
    const unsigned short* r0 = Ywh + (((size_t)(b*96 + 32 + c2))*16 + 2*u)*256 + p;
    const unsigned short* r1 = r0 + 256;
    u16x4 o0, o1;
    #pragma unroll
    for (int k = 0; k < 4; ++k){
      unsigned short a0 = r0[k],   b0 = r1[k];
      unsigned short a1 = r0[4+k], b1 = r1[4+k];
      o0[k] = a0 > b0 ? a0 : b0;
      o1[k] = a1 > b1 ? a1 : b1;
    }
    *(u16x4*)(g_ + ((size_t)(b*64 + c2))*NM + t*8)     = o0;
    *(u16x4*)(g_ + ((size_t)(b*64 + c2))*NM + t*8 + 4) = o1;
  }
}

// ---------------- K4: flash attention, key-split x2 (no-max softmax: associative) ----------------
__global__ __launch_bounds__(256, 4) void k4_attn(
    const unsigned short* __restrict__ thetaT, const unsigned short* __restrict__ phiT,
    const unsigned short* __restrict__ g_, unsigned short* __restrict__ pacc,
    float* __restrict__ lsumA){
  __shared__ __align__(16) unsigned short phi_lds[2][32][40];
  __shared__ __align__(16) unsigned short g_lds[2][64][40];
  __shared__ __align__(16) unsigned short P_lds[4][16][40];

  int bx = blockIdx.x;                               // 1024
  int b = bx >> 8, qb = (bx >> 1) & 127, kh = bx & 1;
  int tid = threadIdx.x;
  int lane = tid & 63, wv = tid >> 6;
  int ln = lane & 15, gq = lane >> 4;
  int nq = qb*128 + wv*32;                           // 32 queries per wave (2 tiles)
  int ch0 = kh * 32;                                 // this block's 32 key-chunks

  const unsigned short* thb = thetaT + (size_t)b*NN*32;
  const unsigned short* phb = phiT   + (size_t)b*NM*32;
  const unsigned short* gb  = g_     + (size_t)b*64*NM;

  bf16x8 thf0 = *(const bf16x8*)(thb + (size_t)(nq + ln)*32 + gq*8);
  bf16x8 thf1 = *(const bf16x8*)(thb + (size_t)(nq + 16 + ln)*32 + gq*8);

  f32x4 acc[2][4];
  #pragma unroll
  for (int q = 0; q < 2; ++q)
    #pragma unroll
    for (int c2t = 0; c2t < 4; ++c2t) acc[q][c2t] = (f32x4){0.f,0.f,0.f,0.f};
  float lsum0 = 0.f, lsum1 = 0.f;

  // staging: g by all 256 threads; phi by tid<128
  int gr = tid >> 2, gp = tid & 3;
  const unsigned short* sgp_g = gb + (size_t)gr*NM + ch0*32 + gp*8;
  unsigned short* slg0 = &g_lds[0][gr][gp*8];
  unsigned short* slg1 = &g_lds[1][gr][gp*8];
  bool hasphi = tid < 128;
  int pr = (tid >> 2) & 31, pp = tid & 3;
  const unsigned short* sgp_p = phb + ((size_t)(ch0*32 + pr))*32 + pp*8;
  unsigned short* slp0 = &phi_lds[0][pr][pp*8];
  unsigned short* slp1 = &phi_lds[1][pr][pp*8];

  { bf16x8 srg = *(const bf16x8*)(sgp_g); *(bf16x8*)slg0 = srg; }
  if (hasphi){ bf16x8 srp = *(const bf16x8*)(sgp_p); *(bf16x8*)slp0 = srp; }
  __syncthreads();

  bf16x8 srg_n = {}, srp_n = {};
  for (int lc = 0; lc < 32; ++lc){
    int cur = lc & 1;
    if (lc + 1 < 32){                             // issue-early (T14)
      srg_n = *(const bf16x8*)(sgp_g + (size_t)(lc+1)*32);
      if (hasphi) srp_n = *(const bf16x8*)(sgp_p + (size_t)(lc+1)*1024);
    }
    bf16x8 pf0 = *(const bf16x8*)(&phi_lds[cur][ln][gq*8]);
    bf16x8 pf1 = *(const bf16x8*)(&phi_lds[cur][16+ln][gq*8]);
    bf16x8 gf0 = *(const bf16x8*)(&g_lds[cur][ln][gq*8]);
    bf16x8 gf1 = *(const bf16x8*)(&g_lds[cur][16+ln][gq*8]);
    bf16x8 gf2 = *(const bf16x8*)(&g_lds[cur][32+ln][gq*8]);
    bf16x8 gf3 = *(const bf16x8*)(&g_lds[cur][48+ln][gq*8]);
    f32x4 z = {0.f,0.f,0.f,0.f};

    // ---- q tile 0 ----
    {
      f32x4 s0 = MFMA16(pf0, thf0, z);
      f32x4 s1 = MFMA16(pf1, thf0, z);
      float p0[4], p1[4];
      #pragma unroll
      for (int i = 0; i < 4; ++i){ p0[i] = __expf(s0[i]); p1[i] = __expf(s1[i]); }
      lsum0 += ((p0[0]+p0[1]) + (p0[2]+p0[3])) + ((p1[0]+p1[1]) + (p1[2]+p1[3]));
      u32x2 w0 = { packbf2(p0[0],p0[1]), packbf2(p0[2],p0[3]) };
      u32x2 w1 = { packbf2(p1[0],p1[1]), packbf2(p1[2],p1[3]) };
      *(u32x2*)(&P_lds[wv][ln][gq*4])      = w0;
      *(u32x2*)(&P_lds[wv][ln][16+gq*4])   = w1;
      bf16x8 paf = *(const bf16x8*)(&P_lds[wv][ln][gq*8]);
      acc[0][0] = MFMA16(paf, gf0, acc[0][0]);
      acc[0][1] = MFMA16(paf, gf1, acc[0][1]);
      acc[0][2] = MFMA16(paf, gf2, acc[0][2]);
      acc[0][3] = MFMA16(paf, gf3, acc[0][3]);
    }
    // ---- q tile 1 ----
    {
      f32x4 s0 = MFMA16(pf0, thf1, z);
      f32x4 s1 = MFMA16(pf1, thf1, z);
      float p0[4], p1[4];
      #pragma unroll
      for (int i = 0; i < 4; ++i){ p0[i] = __expf(s0[i]); p1[i] = __expf(s1[i]); }
      lsum1 += ((p0[0]+p0[1]) + (p0[2]+p0[3])) + ((p1[0]+p1[1]) + (p1[2]+p1[3]));
      u32x2 w0 = { packbf2(p0[0],p0[1]), packbf2(p0[2],p0[3]) };
      u32x2 w1 = { packbf2(p1[0],p1[1]), packbf2(p1[2],p1[3]) };
      *(u32x2*)(&P_lds[wv][ln][gq*4])      = w0;
      *(u32x2*)(&P_lds[wv][ln][16+gq*4])   = w1;
      bf16x8 paf = *(const bf16x8*)(&P_lds[wv][ln][gq*8]);
      acc[1][0] = MFMA16(paf, gf0, acc[1][0]);
      acc[1][1] = MFMA16(paf, gf1, acc[1][1]);
      acc[1][2] = MFMA16(paf, gf2, acc[1][2]);
      acc[1][3] = MFMA16(paf, gf3, acc[1][3]);
    }
    if (lc + 1 < 32){                             // write-late into other buffer
      *(bf16x8*)(((lc+1)&1) ? slg1 : slg0) = srg_n;
      if (hasphi) *(bf16x8*)(((lc+1)&1) ? slp1 : slp0) = srp_n;
    }
    __syncthreads();
  }

  lsum0 += __shfl_xor(lsum0, 16); lsum0 += __shfl_xor(lsum0, 32);
  lsum1 += __shfl_xor(lsum1, 16); lsum1 += __shfl_xor(lsum1, 32);

  // raw (unnormalized) partial acc -> pacc[kh][b][n][64] bf16; lsum -> lsumA[kh][b][n]
  unsigned short* pb = pacc + ((size_t)(kh*NB + b))*NN*64;
  #pragma unroll
  for (int i = 0; i < 4; ++i){
    int r0 = nq + gq*4 + i, r1 = nq + 16 + gq*4 + i;
    #pragma unroll
    for (int c2t = 0; c2t < 4; ++c2t){
      pb[(size_t)r0*64 + c2t*16 + ln] = f2bf(acc[0][c2t][i]);
      pb[(size_t)r1*64 + c2t*16 + ln] = f2bf(acc[1][c2t][i]);
    }
  }
  size_t lbase = ((size_t)(kh*NB + b))*NN;
  if (gq == 0)      lsumA[lbase + nq + ln]      = lsum0;
  else if (gq == 1) lsumA[lbase + nq + 16 + ln] = lsum1;
}

// ---------------- K5: combine halves + out = x + gamma*relu(wo @ ag + bo) ----------------
__device__ __forceinline__ bf16x8 combine8(bf16x8 a, bf16x8 b, float inv){
  bf16x8 r;
  #pragma unroll
  for (int k = 0; k < 8; ++k){
    float f = (bf2f((unsigned short)a[k]) + bf2f((unsigned short)b[k])) * inv;
    r[k] = (short)f2bf(f);
  }
  return r;
}

__global__ __launch_bounds__(256, 4) void k5_out(
    const float* __restrict__ x, const unsigned short* __restrict__ pacc,
    const float* __restrict__ lsumA,
    const unsigned short* __restrict__ wob, const float* __restrict__ bo,
    const float* __restrict__ gamma, float* __restrict__ out){
  int blk = blockIdx.x;                 // NB * NN/64 = 1024
  int b = blk >> 8, nblk = blk & 255;
  int tid = threadIdx.x;
  int lane = tid & 63, w = tid >> 6;
  int ln = lane & 15, gq = lane >> 4;
  int n = nblk*64 + w*16 + ln;

  const unsigned short* p0 = pacc + ((size_t)b*NN + n)*64;
  const unsigned short* p1 = pacc + ((size_t)(NB + b)*NN + n)*64;
  float l = lsumA[(size_t)b*NN + n] + lsumA[(size_t)(NB + b)*NN + n];
  float inv = 1.0f / l;
  bf16x8 a0lo = *(const bf16x8*)(p0 + gq*8);
  bf16x8 a1lo = *(const bf16x8*)(p1 + gq*8);
  bf16x8 a0hi = *(const bf16x8*)(p0 + 32 + gq*8);
  bf16x8 a1hi = *(const bf16x8*)(p1 + 32 + gq*8);
  bf16x8 bfr0 = combine8(a0lo, a1lo, inv);
  bf16x8 bfr1 = combine8(a0hi, a1hi, inv);

  float gam = gamma[0];
  #pragma unroll
  for (int ot = 0; ot < 8; ++ot){
    f32x4 acc = {0.f,0.f,0.f,0.f};
    bf16x8 a0 = *(const bf16x8*)(wob + (ot*16 + ln)*64 + gq*8);
    bf16x8 a1 = *(const bf16x8*)(wob + (ot*16 + ln)*64 + 32 + gq*8);
    acc = MFMA16(a0, bfr0, acc);
    acc = MFMA16(a1, bfr1, acc);
    #pragma unroll
    for (int i = 0; i < 4; ++i){
      int o = ot*16 + gq*4 + i;
      size_t idx = ((size_t)b*128 + o)*NN + n;
      float v = acc[i] + bo[o];
      v = v > 0.f ? v : 0.f;
      out[idx] = x[idx] + gam * v;
    }
  }
}

extern "C" void kernel_launch(void* const* d_in, const int* in_sizes, int n_in,
                              void* d_out, int out_size, void* d_ws, size_t ws_size,
                              hipStream_t stream){
  const float* x   = (const float*)d_in[0];
  const float* wf  = (const float*)d_in[1];
  const float* bfp = (const float*)d_in[2];
  const float* wg  = (const float*)d_in[3];
  const float* bgp = (const float*)d_in[4];
  const float* wh  = (const float*)d_in[5];
  const float* bhp = (const float*)d_in[6];
  const float* wo  = (const float*)d_in[7];
  const float* bo  = (const float*)d_in[8];
  const float* gam = (const float*)d_in[9];
  float* out = (float*)d_out;
  char* ws = (char*)d_ws;

  const size_t OFF_WCAT = 0;                                 // 32KB
  const size_t OFF_WO   = 32768;                             // 16KB
  const size_t OFF_BCAT = 49152;                             // 512B
  const size_t OFF_TH   = 65536;                             // 4MB
  const size_t OFF_YWH  = OFF_TH  + (size_t)NB*NN*32*2;      // 4259840, 3MB
  const size_t OFF_PHI  = OFF_YWH + (size_t)NB*96*16*256*2;  // 7405568, 512KB
  const size_t OFF_G    = OFF_PHI + (size_t)NB*NM*32*2;      // 7929856, 1MB
  const size_t OFF_PACC = OFF_G   + (size_t)NB*64*NM*2;      // 8978432, 16MB
  const size_t OFF_LSUM = OFF_PACC+ (size_t)2*NB*NN*64*2;    // 25755648, 512KB -> end 26279936

  unsigned short* Wcat    = (unsigned short*)(ws + OFF_WCAT);
  unsigned short* wob     = (unsigned short*)(ws + OFF_WO);
  float*          bcat    = (float*)(ws + OFF_BCAT);
  unsigned short* thetaT  = (unsigned short*)(ws + OFF_TH);
  unsigned short* Ywh     = (unsigned short*)(ws + OFF_YWH);
  unsigned short* phiT    = (unsigned short*)(ws + OFF_PHI);
  unsigned short* g_      = (unsigned short*)(ws + OFF_G);
  unsigned short* pacc    = (unsigned short*)(ws + OFF_PACC);
  float*          lsumA   = (float*)(ws + OFF_LSUM);

  k0_prep<<<97, 256, 0, stream>>>(wf, wg, wh, bfp, bgp, bhp, wo, Wcat, wob, bcat);
  k2_conv<<<1024, 256, 0, stream>>>(x, Wcat, bcat, thetaT, Ywh);
  k3_pool<<<384, 256, 0, stream>>>(Ywh, phiT, g_);
  k4_attn<<<1024, 256, 0, stream>>>(thetaT, phiT, g_, pacc, lsumA);
  k5_out<<<1024, 256, 0, stream>>>(x, pacc, lsumA, wob, bo, gam, out);
}